// Round 8
// baseline (252.067 us; speedup 1.0000x reference)
//
#include <hip/hip_runtime.h>
#include <hip/hip_bf16.h>
#include <type_traits>

#define B_ 2
#define S_ 2048
#define D_ 1024
#define H_ 16
#define DH_ 64
#define CACHE_ 2048
#define MAXKV_ 4096

using f32x4  = __attribute__((ext_vector_type(4))) float;
using bf16x8 = __attribute__((ext_vector_type(8))) short;
using bf16x4 = __attribute__((ext_vector_type(4))) short;

__device__ inline short f2bf(float x) {
  __hip_bfloat16 h = __float2bfloat16(x);
  short r;
  __builtin_memcpy(&r, &h, 2);
  return r;
}
__device__ inline void stor(float* p, float x) { *p = x; }
__device__ inline void stor(__hip_bfloat16* p, float x) { *p = __float2bfloat16(x); }

// async global->LDS, 16B per lane. LDS dest = uniform base + lane*16.
__device__ inline void glds16(const short* g, short* l) {
  __builtin_amdgcn_global_load_lds(
      (const __attribute__((address_space(1))) void*)g,
      (__attribute__((address_space(3))) void*)l, 16, 0, 0);
}

// ---------------------------------------------------------------------------
// Fused prep (1888 blocks): qbf cast | cache copies + ckbf | cvT | wqT/woT |
// wkT/wvT.
// ---------------------------------------------------------------------------
__device__ inline void tile_transpose(const float* __restrict__ in,
                                      short* __restrict__ out, int R, int C,
                                      int r0, int c0, int t, float T[64][65]) {
#pragma unroll
  for (int p = 0; p < 16; ++p) {
    int li = t + p * 256;
    int r = li >> 6, c = li & 63;
    T[r][c] = in[(size_t)(r0 + r) * C + c0 + c];
  }
  __syncthreads();
#pragma unroll
  for (int p = 0; p < 16; ++p) {
    int li = t + p * 256;
    int c = li >> 6, r = li & 63;
    out[(size_t)(c0 + c) * R + r0 + r] = f2bf(T[r][c]);
  }
}

__global__ __launch_bounds__(256) void prep_kernel(
    const float* __restrict__ q, const float* __restrict__ ck,
    const float* __restrict__ cv, const float* __restrict__ wq,
    const float* __restrict__ wk, const float* __restrict__ wv,
    const float* __restrict__ wo, short* __restrict__ qbf,
    float4* __restrict__ kc, float4* __restrict__ vc,
    short* __restrict__ ckbf, short* __restrict__ cvT,
    short* __restrict__ wqT, short* __restrict__ wkT,
    short* __restrict__ wvT, short* __restrict__ woT) {
  __shared__ float T[64][65];
  const int bx = blockIdx.x, t = threadIdx.x;
  if (bx < 1024) {  // q -> qbf
    int base = bx * 4096 + t * 4;
#pragma unroll
    for (int p = 0; p < 4; ++p) {
      int i = base + p * 1024;
      float4 f = *(const float4*)&q[i];
      bf16x4 s;
      s[0] = f2bf(f.x); s[1] = f2bf(f.y); s[2] = f2bf(f.z); s[3] = f2bf(f.w);
      *(bf16x4*)&qbf[i] = s;
    }
  } else if (bx < 1280) {  // cache copy + ckbf
    int idx = (bx - 1024) * 256 + t;  // [0, 65536)
    const int per_b = CACHE_ * DH_ / 4;
    int b = idx / per_b, rem = idx % per_b;
    int dst = b * (MAXKV_ * DH_ / 4) + rem;
    float4 a = ((const float4*)ck)[idx], c = ((const float4*)cv)[idx];
    kc[dst] = a;
    vc[dst] = c;
    bf16x4 s;
    s[0] = f2bf(a.x); s[1] = f2bf(a.y); s[2] = f2bf(a.z); s[3] = f2bf(a.w);
    *(bf16x4*)&ckbf[idx * 4] = s;
  } else if (bx < 1344) {  // cvT
    int tt = bx - 1280;
    int b = tt >> 5, tile = tt & 31;
    tile_transpose(cv + (size_t)b * CACHE_ * DH_, cvT + (size_t)b * DH_ * CACHE_,
                   CACHE_, DH_, tile * 64, 0, t, T);
  } else if (bx < 1856) {  // wqT / woT
    int tt = bx - 1344;
    int sel = tt >> 8;
    tt &= 255;
    tile_transpose(sel ? wo : wq, sel ? woT : wqT, D_, D_, (tt >> 4) * 64,
                   (tt & 15) * 64, t, T);
  } else {  // wkT / wvT
    int tt = bx - 1856;
    int sel = tt >> 4, tile = tt & 15;
    tile_transpose(sel ? wv : wk, sel ? wvT : wkT, D_, DH_, tile * 64, 0, t, T);
  }
}

// ---------------------------------------------------------------------------
// k/v projections. BM=32, BN=64, BK=32, 256 thr, 256 blocks total.
// blockIdx.z selects (k,wkT,kc) or (v,wvT,vc). kc/vc mapped f32 store.
// ---------------------------------------------------------------------------
__global__ __launch_bounds__(256) void gemm_kv(
    const float* __restrict__ A, const short* __restrict__ Bt,
    float* __restrict__ C, int K, const float* __restrict__ A2,
    const short* __restrict__ Bt2, float* __restrict__ C2) {
  if (blockIdx.z) { A = A2; Bt = Bt2; C = C2; }
  __shared__ __align__(16) short As[32 * 40];
  __shared__ __align__(16) short Bs[64 * 40];
  const int t = threadIdx.x;
  const int w = t >> 6, lane = t & 63, lx = lane & 15, quad = lane >> 4;
  const int row_base = (w & 1) * 16, col_base = (w >> 1) * 32;
  const int row0 = blockIdx.x * 32;

  f32x4 acc[2];
  acc[0] = (f32x4){0.f, 0.f, 0.f, 0.f};
  acc[1] = (f32x4){0.f, 0.f, 0.f, 0.f};

  for (int k0 = 0; k0 < K; k0 += 32) {
    {
      int row = t >> 3, kk0 = (t & 7) * 4;
      float4 f = *(const float4*)&A[(size_t)(row0 + row) * K + k0 + kk0];
      bf16x4 s;
      s[0] = f2bf(f.x); s[1] = f2bf(f.y); s[2] = f2bf(f.z); s[3] = f2bf(f.w);
      *(bf16x4*)&As[row * 40 + kk0] = s;
    }
    {
      int row = t >> 2, kk0 = (t & 3) * 8;
      *(bf16x8*)&Bs[row * 40 + kk0] =
          *(const bf16x8*)&Bt[(size_t)row * K + k0 + kk0];
    }
    __syncthreads();
    bf16x8 a = *(bf16x8*)&As[(row_base + lx) * 40 + quad * 8];
#pragma unroll
    for (int cb = 0; cb < 2; ++cb) {
      bf16x8 b = *(bf16x8*)&Bs[(col_base + cb * 16 + lx) * 40 + quad * 8];
      acc[cb] = __builtin_amdgcn_mfma_f32_16x16x32_bf16(a, b, acc[cb], 0, 0, 0);
    }
    __syncthreads();
  }

#pragma unroll
  for (int cb = 0; cb < 2; ++cb)
#pragma unroll
    for (int reg = 0; reg < 4; ++reg) {
      int r = row0 + row_base + quad * 4 + reg;
      int c = col_base + cb * 16 + lx;
      int bb = r >> 11, s = r & 2047;
      C[(size_t)bb * (MAXKV_ * DH_) + (size_t)(CACHE_ + s) * DH_ + c] =
          acc[cb][reg];
    }
}

// ---------------------------------------------------------------------------
// Big MFMA GEMM, glds staging, 512 threads (8 waves/CU at grid=256).
// C = A(MxK bf16) @ Bt^T (Bt: NxK bf16). BM=BN=128, BK=32.
// Wave w: rows (w>>1)*32, cols (w&1)*64 -> 2x4 frags, 8 MFMA/iter.
// ---------------------------------------------------------------------------
template <typename TC>
__global__ __launch_bounds__(512) void gemm_glds(
    const short* __restrict__ A, const short* __restrict__ Bt,
    TC* __restrict__ C, int M, int N, int K, float scale) {
  __shared__ __align__(16) short As[128 * 32];
  __shared__ __align__(16) short Bs[128 * 32];
  const int t = threadIdx.x;
  const int w = t >> 6, lane = t & 63, lx = lane & 15, quad = lane >> 4;
  const int row0 = blockIdx.x * 128, col0 = blockIdx.y * 128;
  const int row_base = (w >> 1) * 32, col_base = (w & 1) * 64;

  // wave w stages 16 rows of A-tile and 16 rows of B-tile
  const short* Ag = A + (size_t)(row0 + w * 16 + (lane >> 2)) * K + (lane & 3) * 8;
  const short* Bg = Bt + (size_t)(col0 + w * 16 + (lane >> 2)) * K + (lane & 3) * 8;
  short* Al = &As[(w * 16) * 32];
  short* Bl = &Bs[(w * 16) * 32];

  f32x4 acc[2][4];
#pragma unroll
  for (int mb = 0; mb < 2; ++mb)
#pragma unroll
    for (int cb = 0; cb < 4; ++cb) acc[mb][cb] = (f32x4){0.f, 0.f, 0.f, 0.f};

  for (int k0 = 0; k0 < K; k0 += 32) {
    glds16(Ag + k0, Al);
    glds16(Bg + k0, Bl);
    __syncthreads();
    bf16x8 a[2], b[4];
#pragma unroll
    for (int mb = 0; mb < 2; ++mb)
      a[mb] = *(bf16x8*)&As[(row_base + mb * 16 + lx) * 32 + quad * 8];
#pragma unroll
    for (int cb = 0; cb < 4; ++cb)
      b[cb] = *(bf16x8*)&Bs[(col_base + cb * 16 + lx) * 32 + quad * 8];
#pragma unroll
    for (int mb = 0; mb < 2; ++mb)
#pragma unroll
      for (int cb = 0; cb < 4; ++cb)
        acc[mb][cb] = __builtin_amdgcn_mfma_f32_16x16x32_bf16(
            a[mb], b[cb], acc[mb][cb], 0, 0, 0);
    __syncthreads();
  }

#pragma unroll
  for (int mb = 0; mb < 2; ++mb)
#pragma unroll
    for (int cb = 0; cb < 4; ++cb)
#pragma unroll
      for (int reg = 0; reg < 4; ++reg) {
        int r = row0 + row_base + mb * 16 + quad * 4 + reg;
        int c = col0 + col_base + cb * 16 + lx;
        stor(&C[(size_t)r * N + c], acc[mb][cb][reg] * scale);
      }
}

// ---------------------------------------------------------------------------
// Transposed-S MFMA flash attention, paired q-tiles (qtA=p, qtB=31-p).
// S^T = mfma(K-frag, Q-frag): q lands on the lane index -> scalar l per lane,
// packed P writes (bf16x4), packed output stores. K-frag and V-frag reads are
// shared across both strips. Fixed-shift softmax exp(s-10); Q pre-scaled.
// ---------------------------------------------------------------------------
__global__ __launch_bounds__(256) void attention_mfma(
    __hip_bfloat16* __restrict__ qh,   // (B,S,H*DH) bf16, in/out (pre-scaled)
    const short* __restrict__ ckbf,    // (B,CACHE,DH) bf16
    const short* __restrict__ cvT) {   // (B,DH,CACHE) bf16
  __shared__ __align__(16) short Ks[64 * 72];
  __shared__ __align__(16) short Vt[64 * 72];
  __shared__ __align__(16) short PsA[64 * 72];
  __shared__ __align__(16) short PsB[64 * 72];
  const int t = threadIdx.x;
  const int w = t >> 6, lane = t & 63, lx = lane & 15, quad = lane >> 4;
  const int p = blockIdx.x, bh = blockIdx.y;
  const int b = bh >> 4, h = bh & 15;
  const int qtA = p, qtB = 31 - p;
  const int q0A = qtA * 64, q0B = qtB * 64;
  const int qrow = w * 16 + lx;  // this lane's q row (local to strip)
  short* qhp = (short*)qh;

  bf16x8 aqA[2], aqB[2];
#pragma unroll
  for (int kb = 0; kb < 2; ++kb) {
    aqA[kb] = *(const bf16x8*)&qhp[(size_t)(b * S_ + q0A + qrow) * (H_ * DH_) +
                                   h * DH_ + kb * 32 + quad * 8];
    aqB[kb] = *(const bf16x8*)&qhp[(size_t)(b * S_ + q0B + qrow) * (H_ * DH_) +
                                   h * DH_ + kb * 32 + quad * 8];
  }

  f32x4 oA[4], oB[4];  // O^T: [d = dcb*16+quad*4+reg][q = qrow]
#pragma unroll
  for (int d = 0; d < 4; ++d) {
    oA[d] = (f32x4){0.f, 0.f, 0.f, 0.f};
    oB[d] = (f32x4){0.f, 0.f, 0.f, 0.f};
  }
  float lA = 0.f, lB = 0.f;

  for (int kt = 0; kt <= qtB; ++kt) {
    const int k0 = kt * 64;
#pragma unroll
    for (int pp = 0; pp < 2; ++pp) {
      int li = t + pp * 256;
      int row = li >> 3, kk0 = (li & 7) * 8;
      *(bf16x8*)&Ks[row * 72 + kk0] =
          *(const bf16x8*)&ckbf[(size_t)(b * CACHE_ + k0 + row) * DH_ + kk0];
      *(bf16x8*)&Vt[row * 72 + kk0] =
          *(const bf16x8*)&cvT[(size_t)(b * DH_ + row) * CACHE_ + k0 + kk0];
    }
    __syncthreads();

    const bool actA = (kt <= qtA);

    // S^T = K Q^T for both strips, sharing the K fragment reads.
    f32x4 sA[4], sB[4];
#pragma unroll
    for (int cb = 0; cb < 4; ++cb) {
      sA[cb] = (f32x4){0.f, 0.f, 0.f, 0.f};
      sB[cb] = (f32x4){0.f, 0.f, 0.f, 0.f};
    }
#pragma unroll
    for (int cb = 0; cb < 4; ++cb)
#pragma unroll
      for (int kb = 0; kb < 2; ++kb) {
        bf16x8 kf = *(bf16x8*)&Ks[(cb * 16 + lx) * 72 + kb * 32 + quad * 8];
        sB[cb] = __builtin_amdgcn_mfma_f32_16x16x32_bf16(kf, aqB[kb], sB[cb], 0, 0, 0);
        if (actA)
          sA[cb] = __builtin_amdgcn_mfma_f32_16x16x32_bf16(kf, aqA[kb], sA[cb], 0, 0, 0);
      }

    // softmax + packed P write, strip B  (key = cb*16+quad*4+reg, q = qrow)
    {
      const bool diag = (kt == qtB);
#pragma unroll
      for (int cb = 0; cb < 4; ++cb) {
        bf16x4 pk;
#pragma unroll
        for (int reg = 0; reg < 4; ++reg) {
          float x = sB[cb][reg];
          if (diag && (cb * 16 + quad * 4 + reg > qrow)) x = -1e30f;
          float pe = __expf(x - 10.0f);
          lB += pe;
          pk[reg] = f2bf(pe);
        }
        *(bf16x4*)&PsB[qrow * 72 + cb * 16 + quad * 4] = pk;
      }
    }
    if (actA) {
      const bool diag = (kt == qtA);
#pragma unroll
      for (int cb = 0; cb < 4; ++cb) {
        bf16x4 pk;
#pragma unroll
        for (int reg = 0; reg < 4; ++reg) {
          float x = sA[cb][reg];
          if (diag && (cb * 16 + quad * 4 + reg > qrow)) x = -1e30f;
          float pe = __expf(x - 10.0f);
          lA += pe;
          pk[reg] = f2bf(pe);
        }
        *(bf16x4*)&PsA[qrow * 72 + cb * 16 + quad * 4] = pk;
      }
    }

    // O^T += V^T P^T, sharing the V fragment reads across strips.
#pragma unroll
    for (int kb = 0; kb < 2; ++kb) {
      bf16x8 pB = *(bf16x8*)&PsB[qrow * 72 + kb * 32 + quad * 8];
      bf16x8 pA;
      if (actA) pA = *(bf16x8*)&PsA[qrow * 72 + kb * 32 + quad * 8];
#pragma unroll
      for (int dcb = 0; dcb < 4; ++dcb) {
        bf16x8 vf = *(bf16x8*)&Vt[(dcb * 16 + lx) * 72 + kb * 32 + quad * 8];
        oB[dcb] = __builtin_amdgcn_mfma_f32_16x16x32_bf16(vf, pB, oB[dcb], 0, 0, 0);
        if (actA)
          oA[dcb] = __builtin_amdgcn_mfma_f32_16x16x32_bf16(vf, pA, oA[dcb], 0, 0, 0);
      }
    }
    __syncthreads();
  }

  // l lives per-lane (q = qrow); quads hold disjoint key subsets -> 2 shuffles.
  lA += __shfl_xor(lA, 16, 64);
  lA += __shfl_xor(lA, 32, 64);
  lB += __shfl_xor(lB, 16, 64);
  lB += __shfl_xor(lB, 32, 64);
  float iA = 1.f / lA, iB = 1.f / lB;

#pragma unroll
  for (int dcb = 0; dcb < 4; ++dcb) {
    bf16x4 pa, pb;
#pragma unroll
    for (int reg = 0; reg < 4; ++reg) {
      pa[reg] = f2bf(oA[dcb][reg] * iA);
      pb[reg] = f2bf(oB[dcb][reg] * iB);
    }
    size_t col = h * DH_ + dcb * 16 + quad * 4;
    *(bf16x4*)&qhp[(size_t)(b * S_ + q0A + qrow) * (H_ * DH_) + col] = pa;
    *(bf16x4*)&qhp[(size_t)(b * S_ + q0B + qrow) * (H_ * DH_) + col] = pb;
  }
}

extern "C" void kernel_launch(void* const* d_in, const int* in_sizes, int n_in,
                              void* d_out, int out_size, void* d_ws, size_t ws_size,
                              hipStream_t stream) {
  const float* q  = (const float*)d_in[0];
  const float* k  = (const float*)d_in[1];
  const float* v  = (const float*)d_in[2];
  const float* ck = (const float*)d_in[3];
  const float* cv = (const float*)d_in[4];
  const float* wq = (const float*)d_in[5];
  const float* wk = (const float*)d_in[6];
  const float* wv = (const float*)d_in[7];
  const float* wo = (const float*)d_in[8];

  // Outputs f32: out (B,S,D) | kc (B,1,MAXKV,DH) | vc (B,1,MAXKV,DH)
  float* out = (float*)d_out;
  float* kc  = out + (size_t)B_ * S_ * D_;
  float* vc  = kc + (size_t)B_ * MAXKV_ * DH_;

  // qbf (bf16 q) in the first 8 MB of out (dead before final GEMM writes out).
  short* qbf = (short*)d_out;

  // Workspace (bf16), 13.25 MB:
  short* ws   = (short*)d_ws;
  short* qh   = ws;                                   // 4194304 elems
  short* ckbf = qh + (size_t)B_ * S_ * H_ * DH_;      // 262144
  short* cvT  = ckbf + (size_t)B_ * CACHE_ * DH_;     // 262144
  short* wqT  = cvT + (size_t)B_ * CACHE_ * DH_;      // 1048576
  short* wkT  = wqT + (size_t)D_ * H_ * DH_;          // 65536
  short* wvT  = wkT + (size_t)D_ * DH_;               // 65536
  short* woT  = wvT + (size_t)D_ * DH_;               // 1048576

  // 1) fused prep
  prep_kernel<<<1888, 256, 0, stream>>>(q, ck, cv, wq, wk, wv, wo, qbf,
                                        (float4*)kc, (float4*)vc, ckbf, cvT,
                                        wqT, wkT, wvT, woT);
  // 2) kc/vc tails: k@wk and v@wv (256 blocks)
  gemm_kv<<<dim3(128, 1, 2), 256, 0, stream>>>(k, wkT, kc, D_, v, wvT, vc);
  // 3) qh <- (qbf@wq) * 1/sqrt(DH)  (glds GEMM, 512 thr)
  gemm_glds<__hip_bfloat16><<<dim3(32, 8), 512, 0, stream>>>(
      qbf, wqT, (__hip_bfloat16*)qh, B_ * S_, H_ * DH_, D_, 0.125f);
  // 4) transposed-S paired-tile flash attention, in-place qh -> vals
  attention_mfma<<<dim3(16, B_ * H_), 256, 0, stream>>>(
      (__hip_bfloat16*)qh, ckbf, cvT);
  // 5) out <- vals@wo (glds GEMM, 512 thr), f32 store
  gemm_glds<float><<<dim3(32, 8), 512, 0, stream>>>(
      qh, woT, out, B_ * S_, D_, D_, 1.0f);
}

// Round 9
// 220.695 us; speedup vs baseline: 1.1421x; 1.1421x over previous
//
#include <hip/hip_runtime.h>
#include <hip/hip_bf16.h>
#include <type_traits>

#define B_ 2
#define S_ 2048
#define D_ 1024
#define H_ 16
#define DH_ 64
#define CACHE_ 2048
#define MAXKV_ 4096

using f32x4  = __attribute__((ext_vector_type(4))) float;
using bf16x8 = __attribute__((ext_vector_type(8))) short;
using bf16x4 = __attribute__((ext_vector_type(4))) short;

__device__ inline short f2bf(float x) {
  __hip_bfloat16 h = __float2bfloat16(x);
  short r;
  __builtin_memcpy(&r, &h, 2);
  return r;
}
__device__ inline void stor(float* p, float x) { *p = x; }
__device__ inline void stor(__hip_bfloat16* p, float x) { *p = __float2bfloat16(x); }

// async global->LDS, 16B per lane. LDS dest = uniform base + lane*16.
__device__ inline void glds16(const short* g, short* l) {
  __builtin_amdgcn_global_load_lds(
      (const __attribute__((address_space(1))) void*)g,
      (__attribute__((address_space(3))) void*)l, 16, 0, 0);
}

// ---------------------------------------------------------------------------
// Fused prep (1888 blocks): qbf cast | cache copies + ckbf | cvT | wqT/woT |
// wkT/wvT.
// ---------------------------------------------------------------------------
__device__ inline void tile_transpose(const float* __restrict__ in,
                                      short* __restrict__ out, int R, int C,
                                      int r0, int c0, int t, float T[64][65]) {
#pragma unroll
  for (int p = 0; p < 16; ++p) {
    int li = t + p * 256;
    int r = li >> 6, c = li & 63;
    T[r][c] = in[(size_t)(r0 + r) * C + c0 + c];
  }
  __syncthreads();
#pragma unroll
  for (int p = 0; p < 16; ++p) {
    int li = t + p * 256;
    int c = li >> 6, r = li & 63;
    out[(size_t)(c0 + c) * R + r0 + r] = f2bf(T[r][c]);
  }
}

__global__ __launch_bounds__(256) void prep_kernel(
    const float* __restrict__ q, const float* __restrict__ ck,
    const float* __restrict__ cv, const float* __restrict__ wq,
    const float* __restrict__ wk, const float* __restrict__ wv,
    const float* __restrict__ wo, short* __restrict__ qbf,
    float4* __restrict__ kc, float4* __restrict__ vc,
    short* __restrict__ ckbf, short* __restrict__ cvT,
    short* __restrict__ wqT, short* __restrict__ wkT,
    short* __restrict__ wvT, short* __restrict__ woT) {
  __shared__ float T[64][65];
  const int bx = blockIdx.x, t = threadIdx.x;
  if (bx < 1024) {  // q -> qbf
    int base = bx * 4096 + t * 4;
#pragma unroll
    for (int p = 0; p < 4; ++p) {
      int i = base + p * 1024;
      float4 f = *(const float4*)&q[i];
      bf16x4 s;
      s[0] = f2bf(f.x); s[1] = f2bf(f.y); s[2] = f2bf(f.z); s[3] = f2bf(f.w);
      *(bf16x4*)&qbf[i] = s;
    }
  } else if (bx < 1280) {  // cache copy + ckbf
    int idx = (bx - 1024) * 256 + t;  // [0, 65536)
    const int per_b = CACHE_ * DH_ / 4;
    int b = idx / per_b, rem = idx % per_b;
    int dst = b * (MAXKV_ * DH_ / 4) + rem;
    float4 a = ((const float4*)ck)[idx], c = ((const float4*)cv)[idx];
    kc[dst] = a;
    vc[dst] = c;
    bf16x4 s;
    s[0] = f2bf(a.x); s[1] = f2bf(a.y); s[2] = f2bf(a.z); s[3] = f2bf(a.w);
    *(bf16x4*)&ckbf[idx * 4] = s;
  } else if (bx < 1344) {  // cvT
    int tt = bx - 1280;
    int b = tt >> 5, tile = tt & 31;
    tile_transpose(cv + (size_t)b * CACHE_ * DH_, cvT + (size_t)b * DH_ * CACHE_,
                   CACHE_, DH_, tile * 64, 0, t, T);
  } else if (bx < 1856) {  // wqT / woT
    int tt = bx - 1344;
    int sel = tt >> 8;
    tt &= 255;
    tile_transpose(sel ? wo : wq, sel ? woT : wqT, D_, D_, (tt >> 4) * 64,
                   (tt & 15) * 64, t, T);
  } else {  // wkT / wvT
    int tt = bx - 1856;
    int sel = tt >> 4, tile = tt & 15;
    tile_transpose(sel ? wv : wk, sel ? wvT : wkT, D_, DH_, tile * 64, 0, t, T);
  }
}

// ---------------------------------------------------------------------------
// k/v projections. BM=32, BN=64, BK=32, 256 thr, 256 blocks total.
// blockIdx.z selects (k,wkT,kc) or (v,wvT,vc). kc/vc mapped f32 store.
// ---------------------------------------------------------------------------
__global__ __launch_bounds__(256) void gemm_kv(
    const float* __restrict__ A, const short* __restrict__ Bt,
    float* __restrict__ C, int K, const float* __restrict__ A2,
    const short* __restrict__ Bt2, float* __restrict__ C2) {
  if (blockIdx.z) { A = A2; Bt = Bt2; C = C2; }
  __shared__ __align__(16) short As[32 * 40];
  __shared__ __align__(16) short Bs[64 * 40];
  const int t = threadIdx.x;
  const int w = t >> 6, lane = t & 63, lx = lane & 15, quad = lane >> 4;
  const int row_base = (w & 1) * 16, col_base = (w >> 1) * 32;
  const int row0 = blockIdx.x * 32;

  f32x4 acc[2];
  acc[0] = (f32x4){0.f, 0.f, 0.f, 0.f};
  acc[1] = (f32x4){0.f, 0.f, 0.f, 0.f};

  for (int k0 = 0; k0 < K; k0 += 32) {
    {
      int row = t >> 3, kk0 = (t & 7) * 4;
      float4 f = *(const float4*)&A[(size_t)(row0 + row) * K + k0 + kk0];
      bf16x4 s;
      s[0] = f2bf(f.x); s[1] = f2bf(f.y); s[2] = f2bf(f.z); s[3] = f2bf(f.w);
      *(bf16x4*)&As[row * 40 + kk0] = s;
    }
    {
      int row = t >> 2, kk0 = (t & 3) * 8;
      *(bf16x8*)&Bs[row * 40 + kk0] =
          *(const bf16x8*)&Bt[(size_t)row * K + k0 + kk0];
    }
    __syncthreads();
    bf16x8 a = *(bf16x8*)&As[(row_base + lx) * 40 + quad * 8];
#pragma unroll
    for (int cb = 0; cb < 2; ++cb) {
      bf16x8 b = *(bf16x8*)&Bs[(col_base + cb * 16 + lx) * 40 + quad * 8];
      acc[cb] = __builtin_amdgcn_mfma_f32_16x16x32_bf16(a, b, acc[cb], 0, 0, 0);
    }
    __syncthreads();
  }

#pragma unroll
  for (int cb = 0; cb < 2; ++cb)
#pragma unroll
    for (int reg = 0; reg < 4; ++reg) {
      int r = row0 + row_base + quad * 4 + reg;
      int c = col_base + cb * 16 + lx;
      int bb = r >> 11, s = r & 2047;
      C[(size_t)bb * (MAXKV_ * DH_) + (size_t)(CACHE_ + s) * DH_ + c] =
          acc[cb][reg];
    }
}

// ---------------------------------------------------------------------------
// Big MFMA GEMM, glds staging. BM=128, BN=64, BK=32, 256 thr.
// Grid (M/128, N/64) = 512 blocks -> 2 blocks/CU so barrier drains overlap.
// Wave w: rows (w>>1)*64, cols (w&1)*32 -> 4x2 frags, 8 MFMA : 6 ds_read.
// ---------------------------------------------------------------------------
template <typename TC>
__global__ __launch_bounds__(256) void gemm_glds(
    const short* __restrict__ A, const short* __restrict__ Bt,
    TC* __restrict__ C, int M, int N, int K, float scale) {
  __shared__ __align__(16) short As[128 * 32];
  __shared__ __align__(16) short Bs[64 * 32];
  const int t = threadIdx.x;
  const int w = t >> 6, lane = t & 63, lx = lane & 15, quad = lane >> 4;
  const int row0 = blockIdx.x * 128, col0 = blockIdx.y * 64;
  const int row_base = (w >> 1) * 64, col_base = (w & 1) * 32;

  // wave w stages A rows [w*32, w*32+32) (2 glds) and B rows [w*16, w*16+16).
  const short* Ag = A + (size_t)(row0 + w * 32 + (lane >> 2)) * K + (lane & 3) * 8;
  const short* Bg = Bt + (size_t)(col0 + w * 16 + (lane >> 2)) * K + (lane & 3) * 8;
  short* Al = &As[(w * 32) * 32];
  short* Bl = &Bs[(w * 16) * 32];

  f32x4 acc[4][2];
#pragma unroll
  for (int mb = 0; mb < 4; ++mb)
#pragma unroll
    for (int cb = 0; cb < 2; ++cb) acc[mb][cb] = (f32x4){0.f, 0.f, 0.f, 0.f};

  for (int k0 = 0; k0 < K; k0 += 32) {
    glds16(Ag + k0, Al);
    glds16(Ag + 16 * K + k0, Al + 16 * 32);
    glds16(Bg + k0, Bl);
    __syncthreads();
    bf16x8 a[4], b[2];
#pragma unroll
    for (int mb = 0; mb < 4; ++mb)
      a[mb] = *(bf16x8*)&As[(row_base + mb * 16 + lx) * 32 + quad * 8];
#pragma unroll
    for (int cb = 0; cb < 2; ++cb)
      b[cb] = *(bf16x8*)&Bs[(col_base + cb * 16 + lx) * 32 + quad * 8];
#pragma unroll
    for (int mb = 0; mb < 4; ++mb)
#pragma unroll
      for (int cb = 0; cb < 2; ++cb)
        acc[mb][cb] = __builtin_amdgcn_mfma_f32_16x16x32_bf16(
            a[mb], b[cb], acc[mb][cb], 0, 0, 0);
    __syncthreads();
  }

#pragma unroll
  for (int mb = 0; mb < 4; ++mb)
#pragma unroll
    for (int cb = 0; cb < 2; ++cb)
#pragma unroll
      for (int reg = 0; reg < 4; ++reg) {
        int r = row0 + row_base + mb * 16 + quad * 4 + reg;
        int c = col0 + col_base + cb * 16 + lx;
        stor(&C[(size_t)r * N + c], acc[mb][cb][reg] * scale);
      }
}

// ---------------------------------------------------------------------------
// MFMA flash attention, paired q-tiles (round-7 proven version).
// Block p handles strips qtA=p, qtB=31-p (uniform 33 strip-tiles).
// Q pre-scaled by 1/sqrt(DH). Fixed-shift softmax exp(s-10). Single Ps buffer
// (P LDS round-trip is wave-private). In-place output over qh.
// ---------------------------------------------------------------------------
__global__ __launch_bounds__(256) void attention_mfma(
    __hip_bfloat16* __restrict__ qh,   // (B,S,H*DH) bf16, in/out (pre-scaled)
    const short* __restrict__ ckbf,    // (B,CACHE,DH) bf16
    const short* __restrict__ cvT) {   // (B,DH,CACHE) bf16
  __shared__ __align__(16) short Ks[64 * 72];
  __shared__ __align__(16) short Vt[64 * 72];
  __shared__ __align__(16) short Ps[64 * 72];
  const int t = threadIdx.x;
  const int w = t >> 6, lane = t & 63, lx = lane & 15, quad = lane >> 4;
  const int p = blockIdx.x, bh = blockIdx.y;
  const int b = bh >> 4, h = bh & 15;
  const int qtA = p, qtB = 31 - p;
  const int q0A = qtA * 64, q0B = qtB * 64;
  short* qhp = (short*)qh;

  bf16x8 aqA[2], aqB[2];
#pragma unroll
  for (int kb = 0; kb < 2; ++kb) {
    aqA[kb] = *(const bf16x8*)&qhp[(size_t)(b * S_ + q0A + w * 16 + lx) * (H_ * DH_) +
                                   h * DH_ + kb * 32 + quad * 8];
    aqB[kb] = *(const bf16x8*)&qhp[(size_t)(b * S_ + q0B + w * 16 + lx) * (H_ * DH_) +
                                   h * DH_ + kb * 32 + quad * 8];
  }

  f32x4 oA[4], oB[4];
#pragma unroll
  for (int d = 0; d < 4; ++d) {
    oA[d] = (f32x4){0.f, 0.f, 0.f, 0.f};
    oB[d] = (f32x4){0.f, 0.f, 0.f, 0.f};
  }
  float lA[4] = {0.f, 0.f, 0.f, 0.f}, lB[4] = {0.f, 0.f, 0.f, 0.f};

  for (int kt = 0; kt <= qtB; ++kt) {
    const int k0 = kt * 64;
#pragma unroll
    for (int pp = 0; pp < 2; ++pp) {
      int li = t + pp * 256;
      int row = li >> 3, kk0 = (li & 7) * 8;
      *(bf16x8*)&Ks[row * 72 + kk0] =
          *(const bf16x8*)&ckbf[(size_t)(b * CACHE_ + k0 + row) * DH_ + kk0];
      *(bf16x8*)&Vt[row * 72 + kk0] =
          *(const bf16x8*)&cvT[(size_t)(b * DH_ + row) * CACHE_ + k0 + kk0];
    }
    __syncthreads();

    // ---- strip B (always active) ----
    {
      f32x4 accs[4];
#pragma unroll
      for (int cb = 0; cb < 4; ++cb) accs[cb] = (f32x4){0.f, 0.f, 0.f, 0.f};
#pragma unroll
      for (int cb = 0; cb < 4; ++cb)
#pragma unroll
        for (int kb = 0; kb < 2; ++kb) {
          bf16x8 bk = *(bf16x8*)&Ks[(cb * 16 + lx) * 72 + kb * 32 + quad * 8];
          accs[cb] = __builtin_amdgcn_mfma_f32_16x16x32_bf16(aqB[kb], bk, accs[cb], 0, 0, 0);
        }
      const bool diag = (kt == qtB);
#pragma unroll
      for (int cb = 0; cb < 4; ++cb)
#pragma unroll
        for (int reg = 0; reg < 4; ++reg) {
          float x = accs[cb][reg];
          if (diag && (cb * 16 + lx > w * 16 + quad * 4 + reg)) x = -1e30f;
          float pe = __expf(x - 10.0f);
          Ps[(w * 16 + quad * 4 + reg) * 72 + cb * 16 + lx] = f2bf(pe);
          lB[reg] += pe;
        }
#pragma unroll
      for (int kb = 0; kb < 2; ++kb) {
        bf16x8 ap = *(bf16x8*)&Ps[(w * 16 + lx) * 72 + kb * 32 + quad * 8];
#pragma unroll
        for (int d = 0; d < 4; ++d) {
          bf16x8 bv = *(bf16x8*)&Vt[(d * 16 + lx) * 72 + kb * 32 + quad * 8];
          oB[d] = __builtin_amdgcn_mfma_f32_16x16x32_bf16(ap, bv, oB[d], 0, 0, 0);
        }
      }
    }

    // ---- strip A (active while kt <= qtA) ----
    if (kt <= qtA) {
      f32x4 accs[4];
#pragma unroll
      for (int cb = 0; cb < 4; ++cb) accs[cb] = (f32x4){0.f, 0.f, 0.f, 0.f};
#pragma unroll
      for (int cb = 0; cb < 4; ++cb)
#pragma unroll
        for (int kb = 0; kb < 2; ++kb) {
          bf16x8 bk = *(bf16x8*)&Ks[(cb * 16 + lx) * 72 + kb * 32 + quad * 8];
          accs[cb] = __builtin_amdgcn_mfma_f32_16x16x32_bf16(aqA[kb], bk, accs[cb], 0, 0, 0);
        }
      const bool diag = (kt == qtA);
#pragma unroll
      for (int cb = 0; cb < 4; ++cb)
#pragma unroll
        for (int reg = 0; reg < 4; ++reg) {
          float x = accs[cb][reg];
          if (diag && (cb * 16 + lx > w * 16 + quad * 4 + reg)) x = -1e30f;
          float pe = __expf(x - 10.0f);
          Ps[(w * 16 + quad * 4 + reg) * 72 + cb * 16 + lx] = f2bf(pe);
          lA[reg] += pe;
        }
#pragma unroll
      for (int kb = 0; kb < 2; ++kb) {
        bf16x8 ap = *(bf16x8*)&Ps[(w * 16 + lx) * 72 + kb * 32 + quad * 8];
#pragma unroll
        for (int d = 0; d < 4; ++d) {
          bf16x8 bv = *(bf16x8*)&Vt[(d * 16 + lx) * 72 + kb * 32 + quad * 8];
          oA[d] = __builtin_amdgcn_mfma_f32_16x16x32_bf16(ap, bv, oA[d], 0, 0, 0);
        }
      }
    }
    __syncthreads();
  }

#pragma unroll
  for (int off = 1; off < 16; off <<= 1)
#pragma unroll
    for (int reg = 0; reg < 4; ++reg) {
      lA[reg] += __shfl_xor(lA[reg], off, 64);
      lB[reg] += __shfl_xor(lB[reg], off, 64);
    }

#pragma unroll
  for (int d = 0; d < 4; ++d)
#pragma unroll
    for (int reg = 0; reg < 4; ++reg) {
      int col = h * DH_ + d * 16 + lx;
      int qA = q0A + w * 16 + quad * 4 + reg;
      int qB = q0B + w * 16 + quad * 4 + reg;
      qhp[(size_t)(b * S_ + qA) * (H_ * DH_) + col] = f2bf(oA[d][reg] / lA[reg]);
      qhp[(size_t)(b * S_ + qB) * (H_ * DH_) + col] = f2bf(oB[d][reg] / lB[reg]);
    }
}

extern "C" void kernel_launch(void* const* d_in, const int* in_sizes, int n_in,
                              void* d_out, int out_size, void* d_ws, size_t ws_size,
                              hipStream_t stream) {
  const float* q  = (const float*)d_in[0];
  const float* k  = (const float*)d_in[1];
  const float* v  = (const float*)d_in[2];
  const float* ck = (const float*)d_in[3];
  const float* cv = (const float*)d_in[4];
  const float* wq = (const float*)d_in[5];
  const float* wk = (const float*)d_in[6];
  const float* wv = (const float*)d_in[7];
  const float* wo = (const float*)d_in[8];

  // Outputs f32: out (B,S,D) | kc (B,1,MAXKV,DH) | vc (B,1,MAXKV,DH)
  float* out = (float*)d_out;
  float* kc  = out + (size_t)B_ * S_ * D_;
  float* vc  = kc + (size_t)B_ * MAXKV_ * DH_;

  // qbf (bf16 q) in the first 8 MB of out (dead before final GEMM writes out).
  short* qbf = (short*)d_out;

  // Workspace (bf16), 13.25 MB:
  short* ws   = (short*)d_ws;
  short* qh   = ws;                                   // 4194304 elems
  short* ckbf = qh + (size_t)B_ * S_ * H_ * DH_;      // 262144
  short* cvT  = ckbf + (size_t)B_ * CACHE_ * DH_;     // 262144
  short* wqT  = cvT + (size_t)B_ * CACHE_ * DH_;      // 1048576
  short* wkT  = wqT + (size_t)D_ * H_ * DH_;          // 65536
  short* wvT  = wkT + (size_t)D_ * DH_;               // 65536
  short* woT  = wvT + (size_t)D_ * DH_;               // 1048576

  // 1) fused prep
  prep_kernel<<<1888, 256, 0, stream>>>(q, ck, cv, wq, wk, wv, wo, qbf,
                                        (float4*)kc, (float4*)vc, ckbf, cvT,
                                        wqT, wkT, wvT, woT);
  // 2) kc/vc tails: k@wk and v@wv (256 blocks)
  gemm_kv<<<dim3(128, 1, 2), 256, 0, stream>>>(k, wkT, kc, D_, v, wvT, vc);
  // 3) qh <- (qbf@wq) * 1/sqrt(DH)  (glds GEMM, 512 blocks)
  gemm_glds<__hip_bfloat16><<<dim3(32, 16), 256, 0, stream>>>(
      qbf, wqT, (__hip_bfloat16*)qh, B_ * S_, H_ * DH_, D_, 0.125f);
  // 4) paired-tile flash attention (round-7 version), in-place qh -> vals
  attention_mfma<<<dim3(16, B_ * H_), 256, 0, stream>>>(
      (__hip_bfloat16*)qh, ckbf, cvT);
  // 5) out <- vals@wo (glds GEMM, 512 blocks), f32 store
  gemm_glds<float><<<dim3(32, 16), 256, 0, stream>>>(
      qh, woT, out, B_ * S_, D_, D_, 1.0f);
}

// Round 10
// 209.433 us; speedup vs baseline: 1.2036x; 1.0538x over previous
//
#include <hip/hip_runtime.h>
#include <hip/hip_bf16.h>
#include <type_traits>

#define B_ 2
#define S_ 2048
#define D_ 1024
#define H_ 16
#define DH_ 64
#define CACHE_ 2048
#define MAXKV_ 4096

using f32x4  = __attribute__((ext_vector_type(4))) float;
using bf16x8 = __attribute__((ext_vector_type(8))) short;
using bf16x4 = __attribute__((ext_vector_type(4))) short;

__device__ inline short f2bf(float x) {
  __hip_bfloat16 h = __float2bfloat16(x);
  short r;
  __builtin_memcpy(&r, &h, 2);
  return r;
}
__device__ inline void stor(float* p, float x) { *p = x; }
__device__ inline void stor(__hip_bfloat16* p, float x) { *p = __float2bfloat16(x); }

// async global->LDS, 16B per lane. LDS dest = wave-uniform base + lane*16.
__device__ inline void glds16(const short* g, short* l) {
  __builtin_amdgcn_global_load_lds(
      (const __attribute__((address_space(1))) void*)g,
      (__attribute__((address_space(3))) void*)l, 16, 0, 0);
}

// ---------------------------------------------------------------------------
// Fused prep (1888 blocks): qbf cast | cache copies + ckbf | cvT | wqT/woT |
// wkT/wvT.
// ---------------------------------------------------------------------------
__device__ inline void tile_transpose(const float* __restrict__ in,
                                      short* __restrict__ out, int R, int C,
                                      int r0, int c0, int t, float T[64][65]) {
#pragma unroll
  for (int p = 0; p < 16; ++p) {
    int li = t + p * 256;
    int r = li >> 6, c = li & 63;
    T[r][c] = in[(size_t)(r0 + r) * C + c0 + c];
  }
  __syncthreads();
#pragma unroll
  for (int p = 0; p < 16; ++p) {
    int li = t + p * 256;
    int c = li >> 6, r = li & 63;
    out[(size_t)(c0 + c) * R + r0 + r] = f2bf(T[r][c]);
  }
}

__global__ __launch_bounds__(256) void prep_kernel(
    const float* __restrict__ q, const float* __restrict__ ck,
    const float* __restrict__ cv, const float* __restrict__ wq,
    const float* __restrict__ wk, const float* __restrict__ wv,
    const float* __restrict__ wo, short* __restrict__ qbf,
    float4* __restrict__ kc, float4* __restrict__ vc,
    short* __restrict__ ckbf, short* __restrict__ cvT,
    short* __restrict__ wqT, short* __restrict__ wkT,
    short* __restrict__ wvT, short* __restrict__ woT) {
  __shared__ float T[64][65];
  const int bx = blockIdx.x, t = threadIdx.x;
  if (bx < 1024) {  // q -> qbf
    int base = bx * 4096 + t * 4;
#pragma unroll
    for (int p = 0; p < 4; ++p) {
      int i = base + p * 1024;
      float4 f = *(const float4*)&q[i];
      bf16x4 s;
      s[0] = f2bf(f.x); s[1] = f2bf(f.y); s[2] = f2bf(f.z); s[3] = f2bf(f.w);
      *(bf16x4*)&qbf[i] = s;
    }
  } else if (bx < 1280) {  // cache copy + ckbf
    int idx = (bx - 1024) * 256 + t;  // [0, 65536)
    const int per_b = CACHE_ * DH_ / 4;
    int b = idx / per_b, rem = idx % per_b;
    int dst = b * (MAXKV_ * DH_ / 4) + rem;
    float4 a = ((const float4*)ck)[idx], c = ((const float4*)cv)[idx];
    kc[dst] = a;
    vc[dst] = c;
    bf16x4 s;
    s[0] = f2bf(a.x); s[1] = f2bf(a.y); s[2] = f2bf(a.z); s[3] = f2bf(a.w);
    *(bf16x4*)&ckbf[idx * 4] = s;
  } else if (bx < 1344) {  // cvT
    int tt = bx - 1280;
    int b = tt >> 5, tile = tt & 31;
    tile_transpose(cv + (size_t)b * CACHE_ * DH_, cvT + (size_t)b * DH_ * CACHE_,
                   CACHE_, DH_, tile * 64, 0, t, T);
  } else if (bx < 1856) {  // wqT / woT
    int tt = bx - 1344;
    int sel = tt >> 8;
    tt &= 255;
    tile_transpose(sel ? wo : wq, sel ? woT : wqT, D_, D_, (tt >> 4) * 64,
                   (tt & 15) * 64, t, T);
  } else {  // wkT / wvT
    int tt = bx - 1856;
    int sel = tt >> 4, tile = tt & 15;
    tile_transpose(sel ? wv : wk, sel ? wvT : wkT, D_, DH_, tile * 64, 0, t, T);
  }
}

// ---------------------------------------------------------------------------
// k/v projections. BM=32, BN=64, BK=64, 256 thr, 256 blocks total, 16 iters.
// blockIdx.z selects (k,wkT,kc) or (v,wvT,vc). kc/vc mapped f32 store.
// ---------------------------------------------------------------------------
__global__ __launch_bounds__(256) void gemm_kv(
    const float* __restrict__ A, const short* __restrict__ Bt,
    float* __restrict__ C, int K, const float* __restrict__ A2,
    const short* __restrict__ Bt2, float* __restrict__ C2) {
  if (blockIdx.z) { A = A2; Bt = Bt2; C = C2; }
  __shared__ __align__(16) short As[32 * 72];
  __shared__ __align__(16) short Bs[64 * 72];
  const int t = threadIdx.x;
  const int w = t >> 6, lane = t & 63, lx = lane & 15, quad = lane >> 4;
  const int row_base = (w & 1) * 16, col_base = (w >> 1) * 32;
  const int row0 = blockIdx.x * 32;

  f32x4 acc[2];
  acc[0] = (f32x4){0.f, 0.f, 0.f, 0.f};
  acc[1] = (f32x4){0.f, 0.f, 0.f, 0.f};

  for (int k0 = 0; k0 < K; k0 += 64) {
    {  // A: 32 rows x 64 k f32 -> bf16; thread covers row t>>3, k (t&7)*8..+8
      int row = t >> 3, c0 = (t & 7) * 8;
      const float* src = &A[(size_t)(row0 + row) * K + k0 + c0];
      float4 f0 = *(const float4*)src;
      float4 f1 = *(const float4*)(src + 4);
      bf16x4 s0, s1;
      s0[0] = f2bf(f0.x); s0[1] = f2bf(f0.y); s0[2] = f2bf(f0.z); s0[3] = f2bf(f0.w);
      s1[0] = f2bf(f1.x); s1[1] = f2bf(f1.y); s1[2] = f2bf(f1.z); s1[3] = f2bf(f1.w);
      *(bf16x4*)&As[row * 72 + c0] = s0;
      *(bf16x4*)&As[row * 72 + c0 + 4] = s1;
    }
    {  // B: 64 rows x 64 k bf16; thread covers row t>>2, k (t&3)*16..+16
      int row = t >> 2, c0 = (t & 3) * 16;
      const short* src = &Bt[(size_t)row * K + k0 + c0];
      *(bf16x8*)&Bs[row * 72 + c0] = *(const bf16x8*)src;
      *(bf16x8*)&Bs[row * 72 + c0 + 8] = *(const bf16x8*)(src + 8);
    }
    __syncthreads();
#pragma unroll
    for (int kb = 0; kb < 2; ++kb) {
      bf16x8 a = *(bf16x8*)&As[(row_base + lx) * 72 + kb * 32 + quad * 8];
#pragma unroll
      for (int cb = 0; cb < 2; ++cb) {
        bf16x8 b = *(bf16x8*)&Bs[(col_base + cb * 16 + lx) * 72 + kb * 32 + quad * 8];
        acc[cb] = __builtin_amdgcn_mfma_f32_16x16x32_bf16(a, b, acc[cb], 0, 0, 0);
      }
    }
    __syncthreads();
  }

#pragma unroll
  for (int cb = 0; cb < 2; ++cb)
#pragma unroll
    for (int reg = 0; reg < 4; ++reg) {
      int r = row0 + row_base + quad * 4 + reg;
      int c = col_base + cb * 16 + lx;
      int bb = r >> 11, s = r & 2047;
      C[(size_t)bb * (MAXKV_ * DH_) + (size_t)(CACHE_ + s) * DH_ + c] =
          acc[cb][reg];
    }
}

// ---------------------------------------------------------------------------
// Big MFMA GEMM, glds staging, BK=64 via dual 32-wide LDS buffers (keeps the
// proven stride-32 glds lane mapping). BM=128, BN=64, 256 thr, 16 K-iters,
// 16 MFMA : 12 ds_read : 6 glds per wave per iter. Grid 512 = 2 blocks/CU.
// ---------------------------------------------------------------------------
template <typename TC>
__global__ __launch_bounds__(256) void gemm_glds(
    const short* __restrict__ A, const short* __restrict__ Bt,
    TC* __restrict__ C, int M, int N, int K, float scale) {
  __shared__ __align__(16) short As[2][128 * 32];
  __shared__ __align__(16) short Bs[2][64 * 32];
  const int t = threadIdx.x;
  const int w = t >> 6, lane = t & 63, lx = lane & 15, quad = lane >> 4;
  const int row0 = blockIdx.x * 128, col0 = blockIdx.y * 64;
  const int row_base = (w >> 1) * 64, col_base = (w & 1) * 32;

  const short* Ag = A + (size_t)(row0 + w * 32 + (lane >> 2)) * K + (lane & 3) * 8;
  const short* Bg = Bt + (size_t)(col0 + w * 16 + (lane >> 2)) * K + (lane & 3) * 8;
  short* Al0 = &As[0][(w * 32) * 32];
  short* Al1 = &As[1][(w * 32) * 32];
  short* Bl0 = &Bs[0][(w * 16) * 32];
  short* Bl1 = &Bs[1][(w * 16) * 32];

  f32x4 acc[4][2];
#pragma unroll
  for (int mb = 0; mb < 4; ++mb)
#pragma unroll
    for (int cb = 0; cb < 2; ++cb) acc[mb][cb] = (f32x4){0.f, 0.f, 0.f, 0.f};

  for (int k0 = 0; k0 < K; k0 += 64) {
    glds16(Ag + k0, Al0);
    glds16(Ag + 16 * K + k0, Al0 + 16 * 32);
    glds16(Ag + k0 + 32, Al1);
    glds16(Ag + 16 * K + k0 + 32, Al1 + 16 * 32);
    glds16(Bg + k0, Bl0);
    glds16(Bg + k0 + 32, Bl1);
    __syncthreads();
    bf16x8 a[4][2], b[2][2];
#pragma unroll
    for (int mb = 0; mb < 4; ++mb)
#pragma unroll
      for (int kb = 0; kb < 2; ++kb)
        a[mb][kb] = *(bf16x8*)&As[kb][(row_base + mb * 16 + lx) * 32 + quad * 8];
#pragma unroll
    for (int cb = 0; cb < 2; ++cb)
#pragma unroll
      for (int kb = 0; kb < 2; ++kb)
        b[cb][kb] = *(bf16x8*)&Bs[kb][(col_base + cb * 16 + lx) * 32 + quad * 8];
#pragma unroll
    for (int kb = 0; kb < 2; ++kb)
#pragma unroll
      for (int mb = 0; mb < 4; ++mb)
#pragma unroll
        for (int cb = 0; cb < 2; ++cb)
          acc[mb][cb] = __builtin_amdgcn_mfma_f32_16x16x32_bf16(
              a[mb][kb], b[cb][kb], acc[mb][cb], 0, 0, 0);
    __syncthreads();
  }

#pragma unroll
  for (int mb = 0; mb < 4; ++mb)
#pragma unroll
    for (int cb = 0; cb < 2; ++cb)
#pragma unroll
      for (int reg = 0; reg < 4; ++reg) {
        int r = row0 + row_base + mb * 16 + quad * 4 + reg;
        int c = col0 + col_base + cb * 16 + lx;
        stor(&C[(size_t)r * N + c], acc[mb][cb][reg] * scale);
      }
}

// ---------------------------------------------------------------------------
// MFMA flash attention, paired q-tiles (round-7 structure) + register-shared
// K/V fragments across strips (hoisted once per tile: 36 -> 20 ds_read/iter).
// Q pre-scaled by 1/sqrt(DH). Fixed-shift softmax exp(s-10). Single Ps buffer
// (P LDS round-trip is wave-private). In-place output over qh.
// ---------------------------------------------------------------------------
__global__ __launch_bounds__(256) void attention_mfma(
    __hip_bfloat16* __restrict__ qh,   // (B,S,H*DH) bf16, in/out (pre-scaled)
    const short* __restrict__ ckbf,    // (B,CACHE,DH) bf16
    const short* __restrict__ cvT) {   // (B,DH,CACHE) bf16
  __shared__ __align__(16) short Ks[64 * 72];
  __shared__ __align__(16) short Vt[64 * 72];
  __shared__ __align__(16) short Ps[64 * 72];
  const int t = threadIdx.x;
  const int w = t >> 6, lane = t & 63, lx = lane & 15, quad = lane >> 4;
  const int p = blockIdx.x, bh = blockIdx.y;
  const int b = bh >> 4, h = bh & 15;
  const int qtA = p, qtB = 31 - p;
  const int q0A = qtA * 64, q0B = qtB * 64;
  short* qhp = (short*)qh;

  bf16x8 aqA[2], aqB[2];
#pragma unroll
  for (int kb = 0; kb < 2; ++kb) {
    aqA[kb] = *(const bf16x8*)&qhp[(size_t)(b * S_ + q0A + w * 16 + lx) * (H_ * DH_) +
                                   h * DH_ + kb * 32 + quad * 8];
    aqB[kb] = *(const bf16x8*)&qhp[(size_t)(b * S_ + q0B + w * 16 + lx) * (H_ * DH_) +
                                   h * DH_ + kb * 32 + quad * 8];
  }

  f32x4 oA[4], oB[4];
#pragma unroll
  for (int d = 0; d < 4; ++d) {
    oA[d] = (f32x4){0.f, 0.f, 0.f, 0.f};
    oB[d] = (f32x4){0.f, 0.f, 0.f, 0.f};
  }
  float lA[4] = {0.f, 0.f, 0.f, 0.f}, lB[4] = {0.f, 0.f, 0.f, 0.f};

  for (int kt = 0; kt <= qtB; ++kt) {
    const int k0 = kt * 64;
#pragma unroll
    for (int pp = 0; pp < 2; ++pp) {
      int li = t + pp * 256;
      int row = li >> 3, kk0 = (li & 7) * 8;
      *(bf16x8*)&Ks[row * 72 + kk0] =
          *(const bf16x8*)&ckbf[(size_t)(b * CACHE_ + k0 + row) * DH_ + kk0];
      *(bf16x8*)&Vt[row * 72 + kk0] =
          *(const bf16x8*)&cvT[(size_t)(b * DH_ + row) * CACHE_ + k0 + kk0];
    }
    __syncthreads();

    // hoisted K/V fragments, shared by both strips
    bf16x8 bk[4][2], bv[4][2];
#pragma unroll
    for (int cb = 0; cb < 4; ++cb)
#pragma unroll
      for (int kb = 0; kb < 2; ++kb) {
        bk[cb][kb] = *(bf16x8*)&Ks[(cb * 16 + lx) * 72 + kb * 32 + quad * 8];
        bv[cb][kb] = *(bf16x8*)&Vt[(cb * 16 + lx) * 72 + kb * 32 + quad * 8];
      }

    // ---- strip B (always active) ----
    {
      f32x4 accs[4];
#pragma unroll
      for (int cb = 0; cb < 4; ++cb) accs[cb] = (f32x4){0.f, 0.f, 0.f, 0.f};
#pragma unroll
      for (int cb = 0; cb < 4; ++cb)
#pragma unroll
        for (int kb = 0; kb < 2; ++kb)
          accs[cb] = __builtin_amdgcn_mfma_f32_16x16x32_bf16(aqB[kb], bk[cb][kb],
                                                             accs[cb], 0, 0, 0);
      const bool diag = (kt == qtB);
#pragma unroll
      for (int cb = 0; cb < 4; ++cb)
#pragma unroll
        for (int reg = 0; reg < 4; ++reg) {
          float x = accs[cb][reg];
          if (diag && (cb * 16 + lx > w * 16 + quad * 4 + reg)) x = -1e30f;
          float pe = __expf(x - 10.0f);
          Ps[(w * 16 + quad * 4 + reg) * 72 + cb * 16 + lx] = f2bf(pe);
          lB[reg] += pe;
        }
#pragma unroll
      for (int kb = 0; kb < 2; ++kb) {
        bf16x8 ap = *(bf16x8*)&Ps[(w * 16 + lx) * 72 + kb * 32 + quad * 8];
#pragma unroll
        for (int d = 0; d < 4; ++d)
          oB[d] = __builtin_amdgcn_mfma_f32_16x16x32_bf16(ap, bv[d][kb], oB[d], 0, 0, 0);
      }
    }

    // ---- strip A (active while kt <= qtA) ----
    if (kt <= qtA) {
      f32x4 accs[4];
#pragma unroll
      for (int cb = 0; cb < 4; ++cb) accs[cb] = (f32x4){0.f, 0.f, 0.f, 0.f};
#pragma unroll
      for (int cb = 0; cb < 4; ++cb)
#pragma unroll
        for (int kb = 0; kb < 2; ++kb)
          accs[cb] = __builtin_amdgcn_mfma_f32_16x16x32_bf16(aqA[kb], bk[cb][kb],
                                                             accs[cb], 0, 0, 0);
      const bool diag = (kt == qtA);
#pragma unroll
      for (int cb = 0; cb < 4; ++cb)
#pragma unroll
        for (int reg = 0; reg < 4; ++reg) {
          float x = accs[cb][reg];
          if (diag && (cb * 16 + lx > w * 16 + quad * 4 + reg)) x = -1e30f;
          float pe = __expf(x - 10.0f);
          Ps[(w * 16 + quad * 4 + reg) * 72 + cb * 16 + lx] = f2bf(pe);
          lA[reg] += pe;
        }
#pragma unroll
      for (int kb = 0; kb < 2; ++kb) {
        bf16x8 ap = *(bf16x8*)&Ps[(w * 16 + lx) * 72 + kb * 32 + quad * 8];
#pragma unroll
        for (int d = 0; d < 4; ++d)
          oA[d] = __builtin_amdgcn_mfma_f32_16x16x32_bf16(ap, bv[d][kb], oA[d], 0, 0, 0);
      }
    }
    __syncthreads();
  }

#pragma unroll
  for (int off = 1; off < 16; off <<= 1)
#pragma unroll
    for (int reg = 0; reg < 4; ++reg) {
      lA[reg] += __shfl_xor(lA[reg], off, 64);
      lB[reg] += __shfl_xor(lB[reg], off, 64);
    }

#pragma unroll
  for (int d = 0; d < 4; ++d)
#pragma unroll
    for (int reg = 0; reg < 4; ++reg) {
      int col = h * DH_ + d * 16 + lx;
      int qA = q0A + w * 16 + quad * 4 + reg;
      int qB = q0B + w * 16 + quad * 4 + reg;
      qhp[(size_t)(b * S_ + qA) * (H_ * DH_) + col] = f2bf(oA[d][reg] / lA[reg]);
      qhp[(size_t)(b * S_ + qB) * (H_ * DH_) + col] = f2bf(oB[d][reg] / lB[reg]);
    }
}

extern "C" void kernel_launch(void* const* d_in, const int* in_sizes, int n_in,
                              void* d_out, int out_size, void* d_ws, size_t ws_size,
                              hipStream_t stream) {
  const float* q  = (const float*)d_in[0];
  const float* k  = (const float*)d_in[1];
  const float* v  = (const float*)d_in[2];
  const float* ck = (const float*)d_in[3];
  const float* cv = (const float*)d_in[4];
  const float* wq = (const float*)d_in[5];
  const float* wk = (const float*)d_in[6];
  const float* wv = (const float*)d_in[7];
  const float* wo = (const float*)d_in[8];

  // Outputs f32: out (B,S,D) | kc (B,1,MAXKV,DH) | vc (B,1,MAXKV,DH)
  float* out = (float*)d_out;
  float* kc  = out + (size_t)B_ * S_ * D_;
  float* vc  = kc + (size_t)B_ * MAXKV_ * DH_;

  // qbf (bf16 q) in the first 8 MB of out (dead before final GEMM writes out).
  short* qbf = (short*)d_out;

  // Workspace (bf16), 13.25 MB:
  short* ws   = (short*)d_ws;
  short* qh   = ws;                                   // 4194304 elems
  short* ckbf = qh + (size_t)B_ * S_ * H_ * DH_;      // 262144
  short* cvT  = ckbf + (size_t)B_ * CACHE_ * DH_;     // 262144
  short* wqT  = cvT + (size_t)B_ * CACHE_ * DH_;      // 1048576
  short* wkT  = wqT + (size_t)D_ * H_ * DH_;          // 65536
  short* wvT  = wkT + (size_t)D_ * DH_;               // 65536
  short* woT  = wvT + (size_t)D_ * DH_;               // 1048576

  // 1) fused prep
  prep_kernel<<<1888, 256, 0, stream>>>(q, ck, cv, wq, wk, wv, wo, qbf,
                                        (float4*)kc, (float4*)vc, ckbf, cvT,
                                        wqT, wkT, wvT, woT);
  // 2) kc/vc tails: k@wk and v@wv (256 blocks, BK=64)
  gemm_kv<<<dim3(128, 1, 2), 256, 0, stream>>>(k, wkT, kc, D_, v, wvT, vc);
  // 3) qh <- (qbf@wq) * 1/sqrt(DH)  (glds GEMM, BK=64, 512 blocks)
  gemm_glds<__hip_bfloat16><<<dim3(32, 16), 256, 0, stream>>>(
      qbf, wqT, (__hip_bfloat16*)qh, B_ * S_, H_ * DH_, D_, 0.125f);
  // 4) paired-tile flash attention (reg-shared K/V frags), in-place qh -> vals
  attention_mfma<<<dim3(16, B_ * H_), 256, 0, stream>>>(
      (__hip_bfloat16*)qh, ckbf, cvT);
  // 5) out <- vals@wo (glds GEMM, BK=64, 512 blocks), f32 store
  gemm_glds<float><<<dim3(32, 16), 256, 0, stream>>>(
      qh, woT, out, B_ * S_, D_, D_, 1.0f);
}